// Round 18
// baseline (353.398 us; speedup 1.0000x reference)
//
#include <hip/hip_runtime.h>
#include <hip/hip_bf16.h>
#include <math.h>

#define N_   32
#define C_   256
#define T_   128
#define V_   25
#define CTV  (C_ * T_ * V_)   // 819200
#define TV   (T_ * V_)        // 3200
#define EPS_ 1e-5f
#define S_Q  0.35355339059327373f
#define NCOPY 64

typedef __attribute__((ext_vector_type(8))) short bf16x8;
typedef __attribute__((ext_vector_type(4))) float f32x4;
typedef __attribute__((ext_vector_type(4))) unsigned short u16x4;

__device__ inline ushort f2b(float f) {
    __hip_bfloat16 h = __float2bfloat16(f);
    return *reinterpret_cast<ushort*>(&h);
}
__device__ inline float b2f(ushort u) {
    __hip_bfloat16 h;
    *reinterpret_cast<ushort*>(&h) = u;
    return __bfloat162float(h);
}
__device__ inline float tanh_fast(float x) {
    float xc = fminf(fmaxf(x, -12.f), 12.f);
    float e = __expf(xc + xc);
    return (e - 1.f) * __builtin_amdgcn_rcpf(e + 1.f);
}
#define LD8(p) (*(const bf16x8*)(p))
#define MFMA16(a, b, c) __builtin_amdgcn_mfma_f32_16x16x32_bf16(a, b, c, 0, 0, 0)

// qkvT (swizzled, [32 v][320]): cols 0..63 q(centered) | 64..127 k | 128..191 g | 192..255 pq | 256..319 pk
__device__ inline int qtswz(int v, int col) {
    return v * 320 + ((((col >> 3)) ^ (v & 7)) << 3) + (col & 7);
}
__device__ inline int qvswz(int e, int w) {     // qkvV [256][32]
    return e * 32 + (((w >> 3) ^ (e & 3)) << 3) + (w & 7);
}
__device__ inline int bswz(int v, int c) {      // B tiles / aT [32][256]
    return v * 256 + ((((c >> 3) ^ (v & 7)) << 3) | (c & 7));
}
__device__ inline int pbswz(int h, int v, int w) {  // pbuf [8][32][32] in region X
    return (h * 32 + v) * 32 + (((w >> 3) ^ (v & 3)) << 3) + (w & 7);
}

// ---------------- prep ----------------
__global__ void prep_kernel(const float* __restrict__ qkv_w,
                            const float* __restrict__ attn_w,
                            ushort* __restrict__ Wq, ushort* __restrict__ Wa,
                            float* __restrict__ pe, float* __restrict__ bins) {
    int idx = blockIdx.x * blockDim.x + threadIdx.x;
    int stride = gridDim.x * blockDim.x;
    for (int i = idx; i < 448 * 256; i += stride) {
        float w = qkv_w[i];
        if (i < 64 * 256) w *= S_Q;
        Wq[i] = f2b(w);
    }
    for (int i = idx; i < 256 * 256; i += stride) Wa[i] = f2b(attn_w[i]);
    for (int i = idx; i < C_ * V_; i += stride) {
        int c = i / V_, v = i - c * V_;
        int j2 = c & ~1;
        float ang = (float)v * expf(-logf(10000.0f) * (float)j2 / (float)C_);
        pe[i] = (c & 1) ? cosf(ang) : sinf(ang);
    }
    for (int i = idx; i < NCOPY * 512; i += stride) bins[i] = 0.f;
}

// ---------------- data_bn stats ----------------
__global__ __launch_bounds__(1024) void dbn_kernel(const float* __restrict__ x,
                                                   const float* __restrict__ gamma,
                                                   const float* __restrict__ beta,
                                                   float* __restrict__ a_scale,
                                                   float* __restrict__ a_shift) {
    __shared__ float pgS[32][25], pgQ[32][25];
    int c = blockIdx.x;
    int tid = threadIdx.x, g = tid >> 5, l = tid & 31;
    float s = 0.f, s2 = 0.f;
    if (l < 25) {
        const float* base = x + (size_t)g * CTV + c * TV + l;
        #pragma unroll 8
        for (int t = 0; t < 128; ++t) {
            float v = base[t * 25];
            s += v; s2 += v * v;
        }
        pgS[g][l] = s; pgQ[g][l] = s2;
    }
    __syncthreads();
    if (tid < 25) {
        float S = 0.f, Q = 0.f;
        #pragma unroll
        for (int g2 = 0; g2 < 32; ++g2) { S += pgS[g2][tid]; Q += pgQ[g2][tid]; }
        float inv = 1.0f / 4096.0f;
        float mean = S * inv, var = Q * inv - mean * mean;
        int f = c * 25 + tid;
        float sc = rsqrtf(var + EPS_) * gamma[f];
        a_scale[f] = sc;
        a_shift[f] = beta[f] - mean * sc;
    }
}

// ---------------- bias2 / peproj ----------------
__global__ void mkbias_kernel(const ushort* __restrict__ Wq,
                              const float* __restrict__ qkv_b,
                              const float* __restrict__ a_shift,
                              const float* __restrict__ pe,
                              float* __restrict__ bias2, float* __restrict__ peproj) {
    int id = blockIdx.x * 256 + threadIdx.x;
    if (id < 11200) {
        int o = id / 25, v = id - o * 25;
        float acc = qkv_b[o] * (o < 64 ? S_Q : 1.f);
        for (int c = 0; c < 256; ++c)
            acc = fmaf(b2f(Wq[o * 256 + c]), a_shift[c * 25 + v], acc);
        bias2[id] = acc;
    } else if (id < 14400) {
        int id2 = id - 11200;
        int r = id2 / 25, v = id2 - r * 25;
        float acc = qkv_b[r] * (r < 64 ? S_Q : 1.f);
        for (int c = 0; c < 256; ++c)
            acc = fmaf(b2f(Wq[r * 256 + c]), pe[c * 25 + v], acc);
        peproj[id2] = acc;
    }
}

__global__ void b2sum_kernel(const float* __restrict__ bias2,
                             float* __restrict__ bias2sum) {
    int o = threadIdx.x;   // 64
    float s = 0.f;
    #pragma unroll
    for (int v = 0; v < 25; ++v) s += bias2[o * 25 + v];
    bias2sum[o] = s;
}

// ---------------- fused per-token kernel (skip from LDS, 3 barriers) ----------
// X [0,16384)      Braw -> pbuf [8][32][32] swz (wave-local)
// Y [16384,32768)  Bxn  -> aT
// Z [32768,53248)  qkvT
// W [53248,69632)  qkvV (dedicated)
// [69632,69760)    qmub
__global__ __launch_bounds__(512, 4) void fused_kernel(
        const float* __restrict__ x,
        const ushort* __restrict__ Wq,
        const float* __restrict__ bias2, const float* __restrict__ peproj,
        const float* __restrict__ a_scale, const float* __restrict__ bias2sum,
        const ushort* __restrict__ Wa, const float* __restrict__ attn_b,
        ushort* __restrict__ ybf, float* __restrict__ bins) {
    __shared__ __align__(16) char smem[69760];
    ushort* Braw = (ushort*)smem;
    ushort* pbuf = (ushort*)smem;
    ushort* Bxn  = (ushort*)(smem + 16384);
    ushort* aT   = (ushort*)(smem + 16384);
    ushort* qkvT = (ushort*)(smem + 32768);
    ushort* qkvV = (ushort*)(smem + 53248);
    ushort* qmub = (ushort*)(smem + 69632);

    int n = blockIdx.x >> 7, t = blockIdx.x & 127;
    int tid = threadIdx.x, wave = tid >> 6, lane = tid & 63;
    int lr = lane & 15, lg = lane >> 4;
    const float* xp = x + (size_t)n * CTV + t * V_;
    ushort* yp = ybf + (size_t)n * CTV + t * V_;
    float* mybins = bins + (blockIdx.x & (NCOPY - 1)) * 512;
    const f32x4 zacc = {0.f, 0.f, 0.f, 0.f};
    const bf16x8 zero8 = {0, 0, 0, 0, 0, 0, 0, 0};

    float b2s[4] = {0.f, 0.f, 0.f, 0.f};
    if (wave < 4) {
        #pragma unroll
        for (int i2 = 0; i2 < 4; ++i2)
            b2s[i2] = bias2sum[wave * 16 + lg * 4 + i2];
    }

    // ---- staging: register-ILP prefetch then LDS writes ----
    {
        float xv[13], sc[13];
        #pragma unroll
        for (int j = 0; j < 13; ++j) {
            int i = tid + j * 512;
            if (i < 6400) {
                int c = i / 25, v = i - c * 25;
                xv[j] = xp[c * TV + v];
                sc[j] = a_scale[i];
            }
        }
        #pragma unroll
        for (int j = 0; j < 13; ++j) {
            int i = tid + j * 512;
            if (i < 6400) {
                int c = i / 25, v = i - c * 25;
                int off = bswz(v, c);
                Braw[off] = f2b(xv[j]);
                Bxn[off]  = f2b(xv[j] * sc[j]);
            }
        }
        for (int i = tid; i < 448; i += 512) {
            int v = 25 + (i >> 6), cz = (i & 63) * 4;
            u16x4 z4 = {0, 0, 0, 0};
            *(u16x4*)(Braw + v * 256 + cz) = z4;
            *(u16x4*)(Bxn + v * 256 + cz) = z4;
        }
    }
    __syncthreads();   // B1

    // ---- pq/pk tile (1 per wave), reads Braw; epilogue -> qkvT (Z) ----
    {
        const ushort* Arow = Wq + (wave * 16 + lr) * 256;
        f32x4 a0 = zacc, a1 = zacc;
        #pragma unroll
        for (int kk = 0; kk < 8; ++kk) {
            int k0 = kk * 32 + lg * 8;
            int oct = (((k0 >> 3) ^ (lr & 7)) << 3);
            bf16x8 a  = LD8(Arow + k0);
            bf16x8 b0 = LD8(Braw + lr * 256 + oct);
            bf16x8 b1 = LD8(Braw + (16 + lr) * 256 + oct);
            a0 = MFMA16(a, b0, a0);
            a1 = MFMA16(a, b1, a1);
        }
        int rb = wave * 16 + lg * 4;
        u16x4 r0, r1;
        #pragma unroll
        for (int i2 = 0; i2 < 4; ++i2) {
            int r = rb + i2;
            r0[i2] = f2b(a0[i2] + peproj[r * 25 + lr]);
            r1[i2] = (lr < 9) ? f2b(a1[i2] + peproj[r * 25 + 16 + lr]) : (ushort)0;
        }
        *(u16x4*)(qkvT + qtswz(lr, 192 + rb)) = r0;
        *(u16x4*)(qkvT + qtswz(16 + lr, 192 + rb)) = r1;
    }

    // ---- skip values from Braw (LDS, pre-B2: completes before any pbuf write) ----
    float sk0[2][4], sk1[2][4];
    #pragma unroll
    for (int tt = 0; tt < 2; ++tt)
        #pragma unroll
        for (int i2 = 0; i2 < 4; ++i2) {
            int o = (wave + tt * 8) * 16 + lg * 4 + i2;
            sk0[tt][i2] = b2f(Braw[bswz(lr, o)]);
            sk1[tt][i2] = (lr < 9) ? b2f(Braw[bswz(16 + lr, o)]) : 0.f;
        }

    // ---- q/k/g/v tiles (kk-outer, shared B frags); immediate epilogues ----
    {
        int myTiles = (wave < 4) ? 4 : 3;
        f32x4 acc[4][2];
        #pragma unroll
        for (int i = 0; i < 4; ++i) { acc[i][0] = zacc; acc[i][1] = zacc; }
        #pragma unroll
        for (int kk = 0; kk < 8; ++kk) {
            int k0 = kk * 32 + lg * 8;
            int oct = (((k0 >> 3) ^ (lr & 7)) << 3);
            bf16x8 b0 = LD8(Bxn + lr * 256 + oct);
            bf16x8 b1 = LD8(Bxn + (16 + lr) * 256 + oct);
            #pragma unroll
            for (int tt = 0; tt < 4; ++tt) {
                if (tt < myTiles) {
                    int mt = wave + tt * 8;
                    bf16x8 a = LD8(Wq + (mt * 16 + lr) * 256 + k0);
                    acc[tt][0] = MFMA16(a, b0, acc[tt][0]);
                    acc[tt][1] = MFMA16(a, b1, acc[tt][1]);
                }
            }
        }
        #pragma unroll
        for (int tt = 0; tt < 4; ++tt) {
            if (tt < myTiles) {
                int mt = wave + tt * 8;
                int ob = mt * 16 + lg * 4;
                if (mt < 4) {
                    u16x4 r0, r1;
                    #pragma unroll
                    for (int i2 = 0; i2 < 4; ++i2) {
                        int o = ob + i2;
                        float cs = acc[tt][0][i2] + ((lr < 9) ? acc[tt][1][i2] : 0.f);
                        #pragma unroll
                        for (int mm = 1; mm < 16; mm <<= 1)
                            cs += __shfl_xor(cs, mm, 64);
                        float mu = (cs + b2s[i2]) * 0.04f;
                        ushort mur = f2b(mu);
                        float muf = b2f(mur);
                        r0[i2] = f2b(acc[tt][0][i2] + bias2[o * 25 + lr] - muf);
                        r1[i2] = (lr < 9)
                            ? f2b(acc[tt][1][i2] + bias2[o * 25 + 16 + lr] - muf)
                            : (ushort)0;
                        if (lr == 0) qmub[o] = mur;
                    }
                    *(u16x4*)(qkvT + qtswz(lr, ob)) = r0;
                    *(u16x4*)(qkvT + qtswz(16 + lr, ob)) = r1;
                } else if (mt < 12) {
                    u16x4 r0, r1;
                    #pragma unroll
                    for (int i2 = 0; i2 < 4; ++i2) {
                        int o = ob + i2;
                        r0[i2] = f2b(acc[tt][0][i2] + bias2[o * 25 + lr]);
                        r1[i2] = (lr < 9)
                            ? f2b(acc[tt][1][i2] + bias2[o * 25 + 16 + lr])
                            : (ushort)0;
                    }
                    *(u16x4*)(qkvT + qtswz(lr, ob)) = r0;
                    *(u16x4*)(qkvT + qtswz(16 + lr, ob)) = r1;
                } else {
                    #pragma unroll
                    for (int i2 = 0; i2 < 4; ++i2) {
                        int o = ob + i2;
                        int e = o - 192;
                        qkvV[qvswz(e, lr)] = f2b(acc[tt][0][i2] + bias2[o * 25 + lr]);
                        qkvV[qvswz(e, 16 + lr)] = (lr < 9)
                            ? f2b(acc[tt][1][i2] + bias2[o * 25 + 16 + lr])
                            : (ushort)0;
                    }
                }
            }
        }
    }
    __syncthreads();   // B2: all Braw/Bxn reads + qkvT/qkvV/qmub writes done

    // ---- weights phase (wave = head h) ----
    int h = wave;
    bf16x8 mu8 = LD8(qmub + h * 8);
    bf16x8 aP1[2], aP2[2], bP1[2], bP2[2];
    #pragma unroll
    for (int mi = 0; mi < 2; ++mi) {
        int row = mi * 16 + lr, sx = row & 7;
        const ushort* rp = qkvT + row * 320;
        aP1[mi] = (lg == 0) ? LD8(rp + ((h ^ sx) << 3))
                : (lg == 1) ? LD8(rp + (((24 + h) ^ sx) << 3)) : zero8;
        aP2[mi] = (lg == 0) ? LD8(rp + (((24 + h) ^ sx) << 3))
                : (lg == 1) ? mu8 : zero8;
        bP1[mi] = (lg == 0) ? LD8(rp + (((8 + h) ^ sx) << 3))
                : (lg == 1) ? LD8(rp + (((32 + h) ^ sx) << 3)) : zero8;
        bP2[mi] = (lg == 0) ? LD8(rp + (((32 + h) ^ sx) << 3))
                : (lg == 1) ? LD8(rp + (((16 + h) ^ sx) << 3)) : zero8;
    }
    f32x4 p1[2][2], p2[2][2];
    #pragma unroll
    for (int mi = 0; mi < 2; ++mi)
        #pragma unroll
        for (int ni = 0; ni < 2; ++ni) {
            p1[mi][ni] = MFMA16(aP1[mi], bP1[ni], zacc);
            p2[mi][ni] = MFMA16(aP2[mi], bP2[ni], zacc);
        }
    // (no barrier: pbuf lives in region X and is strictly wave-local)

    // ---- pbuf[h][v][w] = tanh(P1) + tanh(P2) ----
    #pragma unroll
    for (int mi = 0; mi < 2; ++mi)
        #pragma unroll
        for (int ni = 0; ni < 2; ++ni) {
            int w = ni * 16 + lr;
            #pragma unroll
            for (int i2 = 0; i2 < 4; ++i2) {
                int v = mi * 16 + lg * 4 + i2;
                float tw = tanh_fast(p1[mi][ni][i2]) + tanh_fast(p2[mi][ni][i2]);
                pbuf[pbswz(h, v, w)] = (w < 25) ? f2b(tw) : (ushort)0;
            }
        }

    // ---- attn: weights x V -> aT[v][e] ----
    {
        bf16x8 aw[2], bv[2];
        #pragma unroll
        for (int mi = 0; mi < 2; ++mi) {
            int v = mi * 16 + lr;
            aw[mi] = LD8(pbuf + (h * 32 + v) * 32 + ((lg ^ (v & 3)) << 3));
        }
        #pragma unroll
        for (int ni = 0; ni < 2; ++ni) {
            int e = h * 32 + ni * 16 + lr;
            bv[ni] = LD8(qkvV + e * 32 + ((lg ^ (e & 3)) << 3));
        }
        f32x4 at_[2][2];
        #pragma unroll
        for (int mi = 0; mi < 2; ++mi)
            #pragma unroll
            for (int ni = 0; ni < 2; ++ni)
                at_[mi][ni] = MFMA16(aw[mi], bv[ni], zacc);
        #pragma unroll
        for (int mi = 0; mi < 2; ++mi)
            #pragma unroll
            for (int ni = 0; ni < 2; ++ni)
                #pragma unroll
                for (int i2 = 0; i2 < 4; ++i2) {
                    int v = mi * 16 + lg * 4 + i2;
                    int e = h * 32 + ni * 16 + lr;
                    if (v < 25) aT[bswz(v, e)] = f2b(at_[mi][ni][i2]);
                }
    }
    __syncthreads();   // B5: aT complete

    // ---- GEMM2 + bf16 store + bn2 partials ----
    #pragma unroll
    for (int tt = 0; tt < 2; ++tt) {
        int o0 = (wave + tt * 8) * 16;
        const ushort* Arow = Wa + (o0 + lr) * 256;
        f32x4 a0 = zacc, a1 = zacc;
        #pragma unroll
        for (int kk = 0; kk < 8; ++kk) {
            int k0 = kk * 32 + lg * 8;
            int oct = (((k0 >> 3) ^ (lr & 7)) << 3);
            bf16x8 a  = LD8(Arow + k0);
            bf16x8 b0 = LD8(aT + lr * 256 + oct);
            bf16x8 b1 = LD8(aT + (16 + lr) * 256 + oct);
            a0 = MFMA16(a, b0, a0);
            a1 = MFMA16(a, b1, a1);
        }
        #pragma unroll
        for (int i2 = 0; i2 < 4; ++i2) {
            int o = o0 + lg * 4 + i2;
            float bias = attn_b[o];
            float v0 = a0[i2] + bias + sk0[tt][i2];
            yp[o * TV + lr] = f2b(v0);
            float v1 = 0.f;
            if (lr < 9) {
                v1 = a1[i2] + bias + sk1[tt][i2];
                yp[o * TV + 16 + lr] = f2b(v1);
            }
            float cs = v0 + v1, cq = v0 * v0 + v1 * v1;
            #pragma unroll
            for (int mm = 1; mm < 16; mm <<= 1) {
                cs += __shfl_xor(cs, mm, 64);
                cq += __shfl_xor(cq, mm, 64);
            }
            if (lr == 0) {
                atomicAdd(&mybins[o], cs);
                atomicAdd(&mybins[256 + o], cq);
            }
        }
    }
}

// ---------------- bn2 final + apply (bf16 in, f32 out) ----------------
__global__ void bn2_final_kernel(const float* __restrict__ bins,
                                 const float* __restrict__ gamma,
                                 const float* __restrict__ beta,
                                 float* __restrict__ scale,
                                 float* __restrict__ shift) {
    int c = threadIdx.x;
    float s = 0.f, q = 0.f;
    for (int cp = 0; cp < NCOPY; ++cp) {
        s += bins[cp * 512 + c];
        q += bins[cp * 512 + 256 + c];
    }
    float inv = 1.0f / (float)(N_ * TV);
    float mean = s * inv;
    float var = q * inv - mean * mean;
    float sc = rsqrtf(var + EPS_) * gamma[c];
    scale[c] = sc;
    shift[c] = beta[c] - mean * sc;
}

__global__ void bn2_apply_kernel(const ushort* __restrict__ ybf,
                                 float4* __restrict__ out,
                                 const float* __restrict__ scale,
                                 const float* __restrict__ shift) {
    const int total4 = N_ * CTV / 4;
    for (int i = blockIdx.x * blockDim.x + threadIdx.x; i < total4;
         i += gridDim.x * blockDim.x) {
        int c = (i / (TV / 4)) & 255;
        u16x4 yv = *(const u16x4*)(ybf + (size_t)i * 4);
        float sc = scale[c], sh = shift[c];
        float4 v;
        v.x = fmaxf(fmaf(b2f(yv[0]), sc, sh), 0.f);
        v.y = fmaxf(fmaf(b2f(yv[1]), sc, sh), 0.f);
        v.z = fmaxf(fmaf(b2f(yv[2]), sc, sh), 0.f);
        v.w = fmaxf(fmaf(b2f(yv[3]), sc, sh), 0.f);
        out[i] = v;
    }
}

extern "C" void kernel_launch(void* const* d_in, const int* in_sizes, int n_in,
                              void* d_out, int out_size, void* d_ws, size_t ws_size,
                              hipStream_t stream) {
    const float* x      = (const float*)d_in[0];
    const float* qkv_w  = (const float*)d_in[1];
    const float* qkv_b  = (const float*)d_in[2];
    const float* attn_w = (const float*)d_in[3];
    const float* attn_b = (const float*)d_in[4];
    const float* dbn_g  = (const float*)d_in[5];
    const float* dbn_b  = (const float*)d_in[6];
    const float* bn_g   = (const float*)d_in[7];
    const float* bn_b   = (const float*)d_in[8];
    float* out = (float*)d_out;

    char* ws = (char*)d_ws;
    ushort* Wq       = (ushort*)ws;                 // 229376 B
    ushort* Wa       = (ushort*)(ws + 229376);      // 131072 B
    float*  pe       = (float*)(ws + 360448);       // 25600 B
    float*  a_scale  = (float*)(ws + 386048);       // 25600 B
    float*  a_shift  = (float*)(ws + 411648);       // 25600 B
    float*  bias2    = (float*)(ws + 437248);       // 44800 B
    float*  peproj   = (float*)(ws + 482048);       // 12800 B
    float*  bias2sum = (float*)(ws + 494848);       // 256 B
    float*  bins     = (float*)(ws + 495104);       // 131072 B
    float*  bn2_sc   = (float*)(ws + 626176);       // 1024 B
    float*  bn2_sh   = (float*)(ws + 627200);       // 1024 B
    ushort* ybf      = (ushort*)(ws + 628224);      // 52,428,800 B

    prep_kernel<<<256, 256, 0, stream>>>(qkv_w, attn_w, Wq, Wa, pe, bins);
    dbn_kernel<<<C_, 1024, 0, stream>>>(x, dbn_g, dbn_b, a_scale, a_shift);
    mkbias_kernel<<<57, 256, 0, stream>>>(Wq, qkv_b, a_shift, pe, bias2, peproj);
    b2sum_kernel<<<1, 64, 0, stream>>>(bias2, bias2sum);
    fused_kernel<<<N_ * T_, 512, 0, stream>>>(x, Wq, bias2, peproj, a_scale,
                                              bias2sum, Wa, attn_b, ybf, bins);
    bn2_final_kernel<<<1, 256, 0, stream>>>(bins, bn_g, bn_b, bn2_sc, bn2_sh);
    bn2_apply_kernel<<<4096, 256, 0, stream>>>(ybf, (float4*)out, bn2_sc, bn2_sh);
}

// Round 19
// 339.319 us; speedup vs baseline: 1.0415x; 1.0415x over previous
//
#include <hip/hip_runtime.h>
#include <hip/hip_bf16.h>
#include <math.h>

#define N_   32
#define C_   256
#define T_   128
#define V_   25
#define CTV  (C_ * T_ * V_)   // 819200
#define TV   (T_ * V_)        // 3200
#define EPS_ 1e-5f
#define S_Q  0.35355339059327373f
#define NCOPY 64

typedef __attribute__((ext_vector_type(8))) short bf16x8;
typedef __attribute__((ext_vector_type(4))) float f32x4;
typedef __attribute__((ext_vector_type(4))) unsigned short u16x4;

__device__ inline ushort f2b(float f) {
    __hip_bfloat16 h = __float2bfloat16(f);
    return *reinterpret_cast<ushort*>(&h);
}
__device__ inline float b2f(ushort u) {
    __hip_bfloat16 h;
    *reinterpret_cast<ushort*>(&h) = u;
    return __bfloat162float(h);
}
__device__ inline float tanh_fast(float x) {
    float xc = fminf(fmaxf(x, -12.f), 12.f);
    float e = __expf(xc + xc);
    return (e - 1.f) * __builtin_amdgcn_rcpf(e + 1.f);
}
#define LD8(p) (*(const bf16x8*)(p))
#define MFMA16(a, b, c) __builtin_amdgcn_mfma_f32_16x16x32_bf16(a, b, c, 0, 0, 0)

// qkvT (swizzled, [32 v][320]): cols 0..63 q(centered) | 64..127 k | 128..191 g | 192..255 pq | 256..319 pk
__device__ inline int qtswz(int v, int col) {
    return v * 320 + ((((col >> 3)) ^ (v & 7)) << 3) + (col & 7);
}
__device__ inline int qvswz(int e, int w) {     // qkvV [256][32]
    return e * 32 + (((w >> 3) ^ (e & 3)) << 3) + (w & 7);
}
__device__ inline int bswz(int v, int c) {      // B tiles / aT [32][256]
    return v * 256 + ((((c >> 3) ^ (v & 7)) << 3) | (c & 7));
}
__device__ inline int pbswz(int h, int v, int w) {  // pbuf [8][32][32] in region X
    return (h * 32 + v) * 32 + (((w >> 3) ^ (v & 3)) << 3) + (w & 7);
}

// ---------------- prep ----------------
__global__ void prep_kernel(const float* __restrict__ qkv_w,
                            const float* __restrict__ attn_w,
                            ushort* __restrict__ Wq, ushort* __restrict__ Wa,
                            float* __restrict__ pe, float* __restrict__ bins) {
    int idx = blockIdx.x * blockDim.x + threadIdx.x;
    int stride = gridDim.x * blockDim.x;
    for (int i = idx; i < 448 * 256; i += stride) {
        float w = qkv_w[i];
        if (i < 64 * 256) w *= S_Q;
        Wq[i] = f2b(w);
    }
    for (int i = idx; i < 256 * 256; i += stride) Wa[i] = f2b(attn_w[i]);
    for (int i = idx; i < C_ * V_; i += stride) {
        int c = i / V_, v = i - c * V_;
        int j2 = c & ~1;
        float ang = (float)v * expf(-logf(10000.0f) * (float)j2 / (float)C_);
        pe[i] = (c & 1) ? cosf(ang) : sinf(ang);
    }
    for (int i = idx; i < NCOPY * 512; i += stride) bins[i] = 0.f;
}

// ---------------- data_bn stats ----------------
__global__ __launch_bounds__(1024) void dbn_kernel(const float* __restrict__ x,
                                                   const float* __restrict__ gamma,
                                                   const float* __restrict__ beta,
                                                   float* __restrict__ a_scale,
                                                   float* __restrict__ a_shift) {
    __shared__ float pgS[32][25], pgQ[32][25];
    int c = blockIdx.x;
    int tid = threadIdx.x, g = tid >> 5, l = tid & 31;
    float s = 0.f, s2 = 0.f;
    if (l < 25) {
        const float* base = x + (size_t)g * CTV + c * TV + l;
        #pragma unroll 8
        for (int t = 0; t < 128; ++t) {
            float v = base[t * 25];
            s += v; s2 += v * v;
        }
        pgS[g][l] = s; pgQ[g][l] = s2;
    }
    __syncthreads();
    if (tid < 25) {
        float S = 0.f, Q = 0.f;
        #pragma unroll
        for (int g2 = 0; g2 < 32; ++g2) { S += pgS[g2][tid]; Q += pgQ[g2][tid]; }
        float inv = 1.0f / 4096.0f;
        float mean = S * inv, var = Q * inv - mean * mean;
        int f = c * 25 + tid;
        float sc = rsqrtf(var + EPS_) * gamma[f];
        a_scale[f] = sc;
        a_shift[f] = beta[f] - mean * sc;
    }
}

// ---------------- bias2 / peproj ----------------
__global__ void mkbias_kernel(const ushort* __restrict__ Wq,
                              const float* __restrict__ qkv_b,
                              const float* __restrict__ a_shift,
                              const float* __restrict__ pe,
                              float* __restrict__ bias2, float* __restrict__ peproj) {
    int id = blockIdx.x * 256 + threadIdx.x;
    if (id < 11200) {
        int o = id / 25, v = id - o * 25;
        float acc = qkv_b[o] * (o < 64 ? S_Q : 1.f);
        for (int c = 0; c < 256; ++c)
            acc = fmaf(b2f(Wq[o * 256 + c]), a_shift[c * 25 + v], acc);
        bias2[id] = acc;
    } else if (id < 14400) {
        int id2 = id - 11200;
        int r = id2 / 25, v = id2 - r * 25;
        float acc = qkv_b[r] * (r < 64 ? S_Q : 1.f);
        for (int c = 0; c < 256; ++c)
            acc = fmaf(b2f(Wq[r * 256 + c]), pe[c * 25 + v], acc);
        peproj[id2] = acc;
    }
}

__global__ void b2sum_kernel(const float* __restrict__ bias2,
                             float* __restrict__ bias2sum) {
    int o = threadIdx.x;   // 64
    float s = 0.f;
    #pragma unroll
    for (int v = 0; v < 25; ++v) s += bias2[o * 25 + v];
    bias2sum[o] = s;
}

// ---------------- fused per-token kernel (3-barrier, round-17 best) ----------
// X [0,16384)      Braw -> pbuf [8][32][32] swz (wave-local)
// Y [16384,32768)  Bxn  -> aT
// Z [32768,53248)  qkvT
// W [53248,69632)  qkvV (dedicated)
// [69632,69760)    qmub
__global__ __launch_bounds__(512, 4) void fused_kernel(
        const float* __restrict__ x,
        const ushort* __restrict__ Wq,
        const float* __restrict__ bias2, const float* __restrict__ peproj,
        const float* __restrict__ a_scale, const float* __restrict__ bias2sum,
        const ushort* __restrict__ Wa, const float* __restrict__ attn_b,
        ushort* __restrict__ ybf, float* __restrict__ bins) {
    __shared__ __align__(16) char smem[69760];
    ushort* Braw = (ushort*)smem;
    ushort* pbuf = (ushort*)smem;
    ushort* Bxn  = (ushort*)(smem + 16384);
    ushort* aT   = (ushort*)(smem + 16384);
    ushort* qkvT = (ushort*)(smem + 32768);
    ushort* qkvV = (ushort*)(smem + 53248);
    ushort* qmub = (ushort*)(smem + 69632);

    int n = blockIdx.x >> 7, t = blockIdx.x & 127;
    int tid = threadIdx.x, wave = tid >> 6, lane = tid & 63;
    int lr = lane & 15, lg = lane >> 4;
    const float* xp = x + (size_t)n * CTV + t * V_;
    ushort* yp = ybf + (size_t)n * CTV + t * V_;
    float* mybins = bins + (blockIdx.x & (NCOPY - 1)) * 512;
    const f32x4 zacc = {0.f, 0.f, 0.f, 0.f};
    const bf16x8 zero8 = {0, 0, 0, 0, 0, 0, 0, 0};

    float b2s[4] = {0.f, 0.f, 0.f, 0.f};
    if (wave < 4) {
        #pragma unroll
        for (int i2 = 0; i2 < 4; ++i2)
            b2s[i2] = bias2sum[wave * 16 + lg * 4 + i2];
    }

    // ---- staging: register-ILP prefetch then LDS writes ----
    {
        float xv[13], sc[13];
        #pragma unroll
        for (int j = 0; j < 13; ++j) {
            int i = tid + j * 512;
            if (i < 6400) {
                int c = i / 25, v = i - c * 25;
                xv[j] = xp[c * TV + v];
                sc[j] = a_scale[i];
            }
        }
        #pragma unroll
        for (int j = 0; j < 13; ++j) {
            int i = tid + j * 512;
            if (i < 6400) {
                int c = i / 25, v = i - c * 25;
                int off = bswz(v, c);
                Braw[off] = f2b(xv[j]);
                Bxn[off]  = f2b(xv[j] * sc[j]);
            }
        }
        for (int i = tid; i < 448; i += 512) {
            int v = 25 + (i >> 6), cz = (i & 63) * 4;
            u16x4 z4 = {0, 0, 0, 0};
            *(u16x4*)(Braw + v * 256 + cz) = z4;
            *(u16x4*)(Bxn + v * 256 + cz) = z4;
        }
    }
    __syncthreads();   // B1

    // ---- pq/pk tile (1 per wave), reads Braw; epilogue -> qkvT (Z) ----
    {
        const ushort* Arow = Wq + (wave * 16 + lr) * 256;
        f32x4 a0 = zacc, a1 = zacc;
        #pragma unroll
        for (int kk = 0; kk < 8; ++kk) {
            int k0 = kk * 32 + lg * 8;
            int oct = (((k0 >> 3) ^ (lr & 7)) << 3);
            bf16x8 a  = LD8(Arow + k0);
            bf16x8 b0 = LD8(Braw + lr * 256 + oct);
            bf16x8 b1 = LD8(Braw + (16 + lr) * 256 + oct);
            a0 = MFMA16(a, b0, a0);
            a1 = MFMA16(a, b1, a1);
        }
        int rb = wave * 16 + lg * 4;
        u16x4 r0, r1;
        #pragma unroll
        for (int i2 = 0; i2 < 4; ++i2) {
            int r = rb + i2;
            r0[i2] = f2b(a0[i2] + peproj[r * 25 + lr]);
            r1[i2] = (lr < 9) ? f2b(a1[i2] + peproj[r * 25 + 16 + lr]) : (ushort)0;
        }
        *(u16x4*)(qkvT + qtswz(lr, 192 + rb)) = r0;
        *(u16x4*)(qkvT + qtswz(16 + lr, 192 + rb)) = r1;
    }

    // ---- q/k/g/v tiles (kk-outer, shared B frags); immediate epilogues ----
    {
        int myTiles = (wave < 4) ? 4 : 3;
        f32x4 acc[4][2];
        #pragma unroll
        for (int i = 0; i < 4; ++i) { acc[i][0] = zacc; acc[i][1] = zacc; }
        #pragma unroll
        for (int kk = 0; kk < 8; ++kk) {
            int k0 = kk * 32 + lg * 8;
            int oct = (((k0 >> 3) ^ (lr & 7)) << 3);
            bf16x8 b0 = LD8(Bxn + lr * 256 + oct);
            bf16x8 b1 = LD8(Bxn + (16 + lr) * 256 + oct);
            #pragma unroll
            for (int tt = 0; tt < 4; ++tt) {
                if (tt < myTiles) {
                    int mt = wave + tt * 8;
                    bf16x8 a = LD8(Wq + (mt * 16 + lr) * 256 + k0);
                    acc[tt][0] = MFMA16(a, b0, acc[tt][0]);
                    acc[tt][1] = MFMA16(a, b1, acc[tt][1]);
                }
            }
        }
        #pragma unroll
        for (int tt = 0; tt < 4; ++tt) {
            if (tt < myTiles) {
                int mt = wave + tt * 8;
                int ob = mt * 16 + lg * 4;
                if (mt < 4) {
                    u16x4 r0, r1;
                    #pragma unroll
                    for (int i2 = 0; i2 < 4; ++i2) {
                        int o = ob + i2;
                        float cs = acc[tt][0][i2] + ((lr < 9) ? acc[tt][1][i2] : 0.f);
                        #pragma unroll
                        for (int mm = 1; mm < 16; mm <<= 1)
                            cs += __shfl_xor(cs, mm, 64);
                        float mu = (cs + b2s[i2]) * 0.04f;
                        ushort mur = f2b(mu);
                        float muf = b2f(mur);
                        r0[i2] = f2b(acc[tt][0][i2] + bias2[o * 25 + lr] - muf);
                        r1[i2] = (lr < 9)
                            ? f2b(acc[tt][1][i2] + bias2[o * 25 + 16 + lr] - muf)
                            : (ushort)0;
                        if (lr == 0) qmub[o] = mur;
                    }
                    *(u16x4*)(qkvT + qtswz(lr, ob)) = r0;
                    *(u16x4*)(qkvT + qtswz(16 + lr, ob)) = r1;
                } else if (mt < 12) {
                    u16x4 r0, r1;
                    #pragma unroll
                    for (int i2 = 0; i2 < 4; ++i2) {
                        int o = ob + i2;
                        r0[i2] = f2b(acc[tt][0][i2] + bias2[o * 25 + lr]);
                        r1[i2] = (lr < 9)
                            ? f2b(acc[tt][1][i2] + bias2[o * 25 + 16 + lr])
                            : (ushort)0;
                    }
                    *(u16x4*)(qkvT + qtswz(lr, ob)) = r0;
                    *(u16x4*)(qkvT + qtswz(16 + lr, ob)) = r1;
                } else {
                    #pragma unroll
                    for (int i2 = 0; i2 < 4; ++i2) {
                        int o = ob + i2;
                        int e = o - 192;
                        qkvV[qvswz(e, lr)] = f2b(acc[tt][0][i2] + bias2[o * 25 + lr]);
                        qkvV[qvswz(e, 16 + lr)] = (lr < 9)
                            ? f2b(acc[tt][1][i2] + bias2[o * 25 + 16 + lr])
                            : (ushort)0;
                    }
                }
            }
        }
    }
    __syncthreads();   // B2: all Braw/Bxn reads + qkvT/qkvV/qmub writes done

    // ---- skip prefetch (latency hidden under weights+tanh+attn) ----
    float sk0[2][4], sk1[2][4];
    #pragma unroll
    for (int tt = 0; tt < 2; ++tt)
        #pragma unroll
        for (int i2 = 0; i2 < 4; ++i2) {
            int o = (wave + tt * 8) * 16 + lg * 4 + i2;
            sk0[tt][i2] = xp[o * TV + lr];
            sk1[tt][i2] = (lr < 9) ? xp[o * TV + 16 + lr] : 0.f;
        }

    // ---- weights phase (wave = head h) ----
    int h = wave;
    bf16x8 mu8 = LD8(qmub + h * 8);
    bf16x8 aP1[2], aP2[2], bP1[2], bP2[2];
    #pragma unroll
    for (int mi = 0; mi < 2; ++mi) {
        int row = mi * 16 + lr, sx = row & 7;
        const ushort* rp = qkvT + row * 320;
        aP1[mi] = (lg == 0) ? LD8(rp + ((h ^ sx) << 3))
                : (lg == 1) ? LD8(rp + (((24 + h) ^ sx) << 3)) : zero8;
        aP2[mi] = (lg == 0) ? LD8(rp + (((24 + h) ^ sx) << 3))
                : (lg == 1) ? mu8 : zero8;
        bP1[mi] = (lg == 0) ? LD8(rp + (((8 + h) ^ sx) << 3))
                : (lg == 1) ? LD8(rp + (((32 + h) ^ sx) << 3)) : zero8;
        bP2[mi] = (lg == 0) ? LD8(rp + (((32 + h) ^ sx) << 3))
                : (lg == 1) ? LD8(rp + (((16 + h) ^ sx) << 3)) : zero8;
    }
    f32x4 p1[2][2], p2[2][2];
    #pragma unroll
    for (int mi = 0; mi < 2; ++mi)
        #pragma unroll
        for (int ni = 0; ni < 2; ++ni) {
            p1[mi][ni] = MFMA16(aP1[mi], bP1[ni], zacc);
            p2[mi][ni] = MFMA16(aP2[mi], bP2[ni], zacc);
        }
    // (no barrier: pbuf lives in region X and is strictly wave-local)

    // ---- pbuf[h][v][w] = tanh(P1) + tanh(P2) ----
    #pragma unroll
    for (int mi = 0; mi < 2; ++mi)
        #pragma unroll
        for (int ni = 0; ni < 2; ++ni) {
            int w = ni * 16 + lr;
            #pragma unroll
            for (int i2 = 0; i2 < 4; ++i2) {
                int v = mi * 16 + lg * 4 + i2;
                float tw = tanh_fast(p1[mi][ni][i2]) + tanh_fast(p2[mi][ni][i2]);
                pbuf[pbswz(h, v, w)] = (w < 25) ? f2b(tw) : (ushort)0;
            }
        }

    // ---- attn: weights x V -> aT[v][e] ----
    {
        bf16x8 aw[2], bv[2];
        #pragma unroll
        for (int mi = 0; mi < 2; ++mi) {
            int v = mi * 16 + lr;
            aw[mi] = LD8(pbuf + (h * 32 + v) * 32 + ((lg ^ (v & 3)) << 3));
        }
        #pragma unroll
        for (int ni = 0; ni < 2; ++ni) {
            int e = h * 32 + ni * 16 + lr;
            bv[ni] = LD8(qkvV + e * 32 + ((lg ^ (e & 3)) << 3));
        }
        f32x4 at_[2][2];
        #pragma unroll
        for (int mi = 0; mi < 2; ++mi)
            #pragma unroll
            for (int ni = 0; ni < 2; ++ni)
                at_[mi][ni] = MFMA16(aw[mi], bv[ni], zacc);
        #pragma unroll
        for (int mi = 0; mi < 2; ++mi)
            #pragma unroll
            for (int ni = 0; ni < 2; ++ni)
                #pragma unroll
                for (int i2 = 0; i2 < 4; ++i2) {
                    int v = mi * 16 + lg * 4 + i2;
                    int e = h * 32 + ni * 16 + lr;
                    if (v < 25) aT[bswz(v, e)] = f2b(at_[mi][ni][i2]);
                }
    }
    __syncthreads();   // B5: aT complete

    // ---- GEMM2 + bf16 store + bn2 partials ----
    #pragma unroll
    for (int tt = 0; tt < 2; ++tt) {
        int o0 = (wave + tt * 8) * 16;
        const ushort* Arow = Wa + (o0 + lr) * 256;
        f32x4 a0 = zacc, a1 = zacc;
        #pragma unroll
        for (int kk = 0; kk < 8; ++kk) {
            int k0 = kk * 32 + lg * 8;
            int oct = (((k0 >> 3) ^ (lr & 7)) << 3);
            bf16x8 a  = LD8(Arow + k0);
            bf16x8 b0 = LD8(aT + lr * 256 + oct);
            bf16x8 b1 = LD8(aT + (16 + lr) * 256 + oct);
            a0 = MFMA16(a, b0, a0);
            a1 = MFMA16(a, b1, a1);
        }
        #pragma unroll
        for (int i2 = 0; i2 < 4; ++i2) {
            int o = o0 + lg * 4 + i2;
            float bias = attn_b[o];
            float v0 = a0[i2] + bias + sk0[tt][i2];
            yp[o * TV + lr] = f2b(v0);
            float v1 = 0.f;
            if (lr < 9) {
                v1 = a1[i2] + bias + sk1[tt][i2];
                yp[o * TV + 16 + lr] = f2b(v1);
            }
            float cs = v0 + v1, cq = v0 * v0 + v1 * v1;
            #pragma unroll
            for (int mm = 1; mm < 16; mm <<= 1) {
                cs += __shfl_xor(cs, mm, 64);
                cq += __shfl_xor(cq, mm, 64);
            }
            if (lr == 0) {
                atomicAdd(&mybins[o], cs);
                atomicAdd(&mybins[256 + o], cq);
            }
        }
    }
}

// ---------------- bn2 final + apply (bf16 in, f32 out) ----------------
__global__ void bn2_final_kernel(const float* __restrict__ bins,
                                 const float* __restrict__ gamma,
                                 const float* __restrict__ beta,
                                 float* __restrict__ scale,
                                 float* __restrict__ shift) {
    int c = threadIdx.x;
    float s = 0.f, q = 0.f;
    for (int cp = 0; cp < NCOPY; ++cp) {
        s += bins[cp * 512 + c];
        q += bins[cp * 512 + 256 + c];
    }
    float inv = 1.0f / (float)(N_ * TV);
    float mean = s * inv;
    float var = q * inv - mean * mean;
    float sc = rsqrtf(var + EPS_) * gamma[c];
    scale[c] = sc;
    shift[c] = beta[c] - mean * sc;
}

__global__ void bn2_apply_kernel(const ushort* __restrict__ ybf,
                                 float4* __restrict__ out,
                                 const float* __restrict__ scale,
                                 const float* __restrict__ shift) {
    const int total4 = N_ * CTV / 4;
    for (int i = blockIdx.x * blockDim.x + threadIdx.x; i < total4;
         i += gridDim.x * blockDim.x) {
        int c = (i / (TV / 4)) & 255;
        u16x4 yv = *(const u16x4*)(ybf + (size_t)i * 4);
        float sc = scale[c], sh = shift[c];
        float4 v;
        v.x = fmaxf(fmaf(b2f(yv[0]), sc, sh), 0.f);
        v.y = fmaxf(fmaf(b2f(yv[1]), sc, sh), 0.f);
        v.z = fmaxf(fmaf(b2f(yv[2]), sc, sh), 0.f);
        v.w = fmaxf(fmaf(b2f(yv[3]), sc, sh), 0.f);
        out[i] = v;
    }
}

extern "C" void kernel_launch(void* const* d_in, const int* in_sizes, int n_in,
                              void* d_out, int out_size, void* d_ws, size_t ws_size,
                              hipStream_t stream) {
    const float* x      = (const float*)d_in[0];
    const float* qkv_w  = (const float*)d_in[1];
    const float* qkv_b  = (const float*)d_in[2];
    const float* attn_w = (const float*)d_in[3];
    const float* attn_b = (const float*)d_in[4];
    const float* dbn_g  = (const float*)d_in[5];
    const float* dbn_b  = (const float*)d_in[6];
    const float* bn_g   = (const float*)d_in[7];
    const float* bn_b   = (const float*)d_in[8];
    float* out = (float*)d_out;

    char* ws = (char*)d_ws;
    ushort* Wq       = (ushort*)ws;                 // 229376 B
    ushort* Wa       = (ushort*)(ws + 229376);      // 131072 B
    float*  pe       = (float*)(ws + 360448);       // 25600 B
    float*  a_scale  = (float*)(ws + 386048);       // 25600 B
    float*  a_shift  = (float*)(ws + 411648);       // 25600 B
    float*  bias2    = (float*)(ws + 437248);       // 44800 B
    float*  peproj   = (float*)(ws + 482048);       // 12800 B
    float*  bias2sum = (float*)(ws + 494848);       // 256 B
    float*  bins     = (float*)(ws + 495104);       // 131072 B
    float*  bn2_sc   = (float*)(ws + 626176);       // 1024 B
    float*  bn2_sh   = (float*)(ws + 627200);       // 1024 B
    ushort* ybf      = (ushort*)(ws + 628224);      // 52,428,800 B

    prep_kernel<<<256, 256, 0, stream>>>(qkv_w, attn_w, Wq, Wa, pe, bins);
    dbn_kernel<<<C_, 1024, 0, stream>>>(x, dbn_g, dbn_b, a_scale, a_shift);
    mkbias_kernel<<<57, 256, 0, stream>>>(Wq, qkv_b, a_shift, pe, bias2, peproj);
    b2sum_kernel<<<1, 64, 0, stream>>>(bias2, bias2sum);
    fused_kernel<<<N_ * T_, 512, 0, stream>>>(x, Wq, bias2, peproj, a_scale,
                                              bias2sum, Wa, attn_b, ybf, bins);
    bn2_final_kernel<<<1, 256, 0, stream>>>(bins, bn_g, bn_b, bn2_sc, bn2_sh);
    bn2_apply_kernel<<<4096, 256, 0, stream>>>(ybf, (float4*)out, bn2_sc, bn2_sh);
}